// Round 14
// baseline (1629.155 us; speedup 1.0000x reference)
//
#include <hip/hip_runtime.h>
#include <hip/hip_bf16.h>

#define DM 512
#define DI 1024
#define DC 4
#define DTR 32
#define NST 16
#define LSEQ 2048
#define NBATCH 32
#define NCH 32
#define CHL 64    // LSEQ / NCH

typedef __attribute__((ext_vector_type(8))) short b16x8;
typedef __attribute__((ext_vector_type(4))) float fx4;
typedef __attribute__((ext_vector_type(4))) unsigned short u16x4;

__device__ __forceinline__ unsigned short f2bf(float f) {
    union { float f; unsigned u; } x; x.f = f;
    unsigned r = x.u + 0x7fffu + ((x.u >> 16) & 1u);
    return (unsigned short)(r >> 16);
}
__device__ __forceinline__ float bf2f(unsigned short u) {
    union { unsigned u; float f; } x; x.u = ((unsigned)u) << 16;
    return x.f;
}

// ---------------- cast fp32 -> bf16 (vec4) ----------------
__global__ __launch_bounds__(256) void cast_kernel(const float* __restrict__ src,
                                                   unsigned short* __restrict__ dst, int n4) {
    int i = blockIdx.x * 256 + threadIdx.x;
    if (i < n4) {
        fx4 v = *(const fx4*)&src[(size_t)i * 4];
        u16x4 o;
        #pragma unroll
        for (int j = 0; j < 4; j++) o[j] = f2bf(v[j]);
        *(u16x4*)&dst[(size_t)i * 4] = o;
    }
}

// ---------------- MFMA bf16 GEMM: C[m,n] = sum_k A[m,k]*W[n,k] ----------------
// BK==64: T3 1-deep ping-pong double-buffer. STATIC buffer refs (macro BUF 0/1,
// single __shared__ array, no dynamic LDS indexing) + EXPLICIT vmcnt(0) drain
// before every barrier (R4-R6 failures: dynamic-db prefetch relied on compiler
// alias analysis to emit the drain; it didn't). Stage targets the buffer
// released by the immediately-preceding barrier; drained before the next.
// R13 LDS XOR swizzle retained: S(o)=o^(((o>>7)&3)<<5) both-sides (rule #21).
// BK==32 (dt_proj, 1 K-tile): original single-buffer path.
// EPI: 0=f32, 1=bf16, 2=gelu->bf16, 3=softplus->f32, 4=softplus->bf16,
//      5=f32 + bf16 copy of cols<32 into aux (xdbl + dt16 fusion)
template <int BN, int BK, int EPI, bool HAS_BIAS>
__global__ __launch_bounds__(256, 2) void gemm_bf16(const unsigned short* __restrict__ A,
                                                    const unsigned short* __restrict__ W,
                                                    const float* __restrict__ bias,
                                                    void* __restrict__ Cout, int N, int K,
                                                    unsigned short* __restrict__ aux) {
    constexpr int BM = 128;
    constexpr int ASZ = BM * BK;          // shorts
    constexpr int WSZ = BN * BK;
    constexpr int HALF = ASZ + WSZ;
    __shared__ __align__(16) unsigned short lds[(BK == 64 ? 2 : 1) * HALF];
    const int tid = threadIdx.x;
    const int wave = tid >> 6, lane = tid & 63;
    const int lr = lane & 15, lg = lane >> 4;
    // XCD swizzle: same-XCD blocks get consecutive tiles (share A panels in L2)
    const int ntx = gridDim.x;
    const int tot = ntx * gridDim.y;
    const int lin = blockIdx.y * ntx + blockIdx.x;
    const int cpx = tot >> 3;
    const int swz = (lin & 7) * cpx + (lin >> 3);
    const int m0 = (swz / ntx) * BM, n0 = (swz % ntx) * BN;
    const int wm0 = (wave >> 1) * 64, wn0 = (wave & 1) * (BN / 2);
    constexpr int NR = BN / 32;
    fx4 acc[4][NR];
    #pragma unroll
    for (int i = 0; i < 4; i++)
        #pragma unroll
        for (int j = 0; j < NR; j++) acc[i][j] = fx4{0.f, 0.f, 0.f, 0.f};

    if constexpr (BK == 64) {
#define VMCNT0 asm volatile("s_waitcnt vmcnt(0)" ::: "memory")
#define STAGE(BUF, KT)                                                                   \
    do {                                                                                 \
        const int k0s = (KT) * 64;                                                       \
        _Pragma("unroll")                                                                \
        for (int i = 0; i < (BM * 64 / 8) / 256; i++) {                                  \
            int ob = (i * 4 + wave) * 1024;                                              \
            int o = ob + lane * 16;                                                      \
            int s = o ^ (((o >> 7) & 3) << 5);                                           \
            int row = s >> 7, cbyte = s & 127;                                           \
            const unsigned short* g = A + (size_t)(m0 + row) * K + k0s + (cbyte >> 1);   \
            __builtin_amdgcn_global_load_lds(                                            \
                (const __attribute__((address_space(1))) unsigned int*)g,                \
                (__attribute__((address_space(3))) unsigned int*)&lds[(BUF) * HALF +     \
                                                                      (ob >> 1)],       \
                16, 0, 0);                                                               \
        }                                                                                \
        _Pragma("unroll")                                                                \
        for (int i = 0; i < (BN * 64 / 8) / 256; i++) {                                  \
            int ob = (i * 4 + wave) * 1024;                                              \
            int o = ob + lane * 16;                                                      \
            int s = o ^ (((o >> 7) & 3) << 5);                                           \
            int row = s >> 7, cbyte = s & 127;                                           \
            const unsigned short* g = W + (size_t)(n0 + row) * K + k0s + (cbyte >> 1);   \
            __builtin_amdgcn_global_load_lds(                                            \
                (const __attribute__((address_space(1))) unsigned int*)g,                \
                (__attribute__((address_space(3))) unsigned int*)&lds[(BUF) * HALF +     \
                                                                      ASZ + (ob >> 1)], \
                16, 0, 0);                                                               \
        }                                                                                \
    } while (0)
#define COMPUTE(BUF)                                                                     \
    do {                                                                                 \
        _Pragma("unroll")                                                                \
        for (int ks = 0; ks < 2; ks++) {                                                 \
            b16x8 af[4], bfr[NR];                                                        \
            _Pragma("unroll")                                                            \
            for (int mi = 0; mi < 4; mi++) {                                             \
                int ar = wm0 + mi * 16 + lr;                                             \
                int ab = (ar * 64 + ks * 32 + lg * 8) * 2;                               \
                ab ^= (ar & 3) << 5;                                                     \
                af[mi] = *(const b16x8*)&lds[(BUF) * HALF + (ab >> 1)];                  \
            }                                                                            \
            _Pragma("unroll")                                                            \
            for (int ni = 0; ni < NR; ni++) {                                            \
                int wr = wn0 + ni * 16 + lr;                                             \
                int wb = (wr * 64 + ks * 32 + lg * 8) * 2;                               \
                wb ^= (wr & 3) << 5;                                                     \
                bfr[ni] = *(const b16x8*)&lds[(BUF) * HALF + ASZ + (wb >> 1)];           \
            }                                                                            \
            _Pragma("unroll")                                                            \
            for (int mi = 0; mi < 4; mi++)                                               \
                _Pragma("unroll")                                                        \
                for (int ni = 0; ni < NR; ni++)                                          \
                    acc[mi][ni] = __builtin_amdgcn_mfma_f32_16x16x32_bf16(               \
                        af[mi], bfr[ni], acc[mi][ni], 0, 0, 0);                          \
        }                                                                                \
    } while (0)
        const int NT = K >> 6;   // all BK=64 call sites have NT even (8/16/32)
        STAGE(0, 0);
        VMCNT0;
        __syncthreads();
        for (int t = 0; t < NT; t += 2) {
            STAGE(1, t + 1);
            COMPUTE(0);
            VMCNT0;
            __syncthreads();
            if (t + 2 < NT) STAGE(0, t + 2);
            COMPUTE(1);
            VMCNT0;
            __syncthreads();
        }
#undef STAGE
#undef COMPUTE
#undef VMCNT0
    } else {
        // single-buffer path (BK==32; used only for K==32 -> one tile)
        unsigned short* As = lds;
        unsigned short* Ws = lds + ASZ;
        constexpr int GPR = BK / 8;
        for (int k0 = 0; k0 < K; k0 += BK) {
            #pragma unroll
            for (int i = 0; i < (BM * BK / 8) / 256; i++) {
                int cb = (i * 4 + wave) * 64, c = cb + lane;
                int row = c / GPR, kk = (c % GPR) * 8;
                const unsigned short* g = A + (size_t)(m0 + row) * K + k0 + kk;
                __builtin_amdgcn_global_load_lds(
                    (const __attribute__((address_space(1))) unsigned int*)g,
                    (__attribute__((address_space(3))) unsigned int*)&As[cb * 8], 16, 0, 0);
            }
            #pragma unroll
            for (int i = 0; i < (BN * BK / 8) / 256; i++) {
                int cb = (i * 4 + wave) * 64, c = cb + lane;
                int row = c / GPR, kk = (c % GPR) * 8;
                const unsigned short* g = W + (size_t)(n0 + row) * K + k0 + kk;
                __builtin_amdgcn_global_load_lds(
                    (const __attribute__((address_space(1))) unsigned int*)g,
                    (__attribute__((address_space(3))) unsigned int*)&Ws[cb * 8], 16, 0, 0);
            }
            __syncthreads();
            #pragma unroll
            for (int ks = 0; ks < BK / 32; ks++) {
                b16x8 af[4], bfr[NR];
                #pragma unroll
                for (int mi = 0; mi < 4; mi++)
                    af[mi] = *(const b16x8*)&As[(wm0 + mi * 16 + lr) * BK + ks * 32 + lg * 8];
                #pragma unroll
                for (int ni = 0; ni < NR; ni++)
                    bfr[ni] = *(const b16x8*)&Ws[(wn0 + ni * 16 + lr) * BK + ks * 32 + lg * 8];
                #pragma unroll
                for (int mi = 0; mi < 4; mi++)
                    #pragma unroll
                    for (int ni = 0; ni < NR; ni++)
                        acc[mi][ni] = __builtin_amdgcn_mfma_f32_16x16x32_bf16(
                            af[mi], bfr[ni], acc[mi][ni], 0, 0, 0);
            }
            __syncthreads();
        }
    }

    #pragma unroll
    for (int mi = 0; mi < 4; mi++) {
        #pragma unroll
        for (int ni = 0; ni < NR; ni++) {
            #pragma unroll
            for (int j2 = 0; j2 < 4; j2++) {
                int row = m0 + wm0 + mi * 16 + lg * 4 + j2;
                int col = n0 + wn0 + ni * 16 + lr;
                float v = acc[mi][ni][j2];
                if (HAS_BIAS) v += bias[col];
                size_t o = (size_t)row * N + col;
                if (EPI == 0) {
                    ((float*)Cout)[o] = v;
                } else if (EPI == 1) {
                    ((unsigned short*)Cout)[o] = f2bf(v);
                } else if (EPI == 2) {
                    v = 0.5f * v * (1.f + erff(v * 0.70710678118654752f));
                    ((unsigned short*)Cout)[o] = f2bf(v);
                } else if (EPI == 3) {
                    v = (v > 20.f) ? v : log1pf(__expf(v));
                    ((float*)Cout)[o] = v;
                } else if (EPI == 4) {
                    v = (v > 20.f) ? v : log1pf(__expf(v));
                    ((unsigned short*)Cout)[o] = f2bf(v);
                } else {
                    ((float*)Cout)[o] = v;
                    if (col < DTR) aux[(size_t)row * DTR + col] = f2bf(v);
                }
            }
        }
    }
}

// ---------------- depthwise causal conv (4 taps) + SiLU, strip-of-8 rolling window ----
__global__ __launch_bounds__(256) void conv_silu_kernel(const unsigned short* __restrict__ xz16,
                                                        const float* __restrict__ cw,
                                                        const float* __restrict__ cb,
                                                        unsigned short* __restrict__ u16) {
    int idx = blockIdx.x * 256 + threadIdx.x;  // (R/8) * 128
    int strip = idx >> 7;
    int d0 = (idx & 127) << 3;
    int m0 = strip * 8;
    int l0 = m0 & (LSEQ - 1);
    fx4 w0[8];
    float bias[8];
    #pragma unroll
    for (int j = 0; j < 8; j++) {
        bias[j] = cb[d0 + j];
        w0[j] = *(const fx4*)&cw[(d0 + j) * 4];
    }
    float win[3][8];
    #pragma unroll
    for (int t = 0; t < 3; t++) {
        int lm = l0 - 3 + t;
        if (lm >= 0) {
            b16x8 xv = *(const b16x8*)&xz16[(size_t)(m0 - 3 + t) * (2 * DI) + d0];
            #pragma unroll
            for (int i = 0; i < 8; i++) win[t][i] = bf2f((unsigned short)xv[i]);
        } else {
            #pragma unroll
            for (int i = 0; i < 8; i++) win[t][i] = 0.f;
        }
    }
    #pragma unroll
    for (int j = 0; j < 8; j++) {
        float cur[8];
        b16x8 xv = *(const b16x8*)&xz16[(size_t)(m0 + j) * (2 * DI) + d0];
        #pragma unroll
        for (int i = 0; i < 8; i++) cur[i] = bf2f((unsigned short)xv[i]);
        b16x8 o;
        #pragma unroll
        for (int i = 0; i < 8; i++) {
            float v = bias[i] + win[0][i] * w0[i][0] + win[1][i] * w0[i][1] +
                      win[2][i] * w0[i][2] + cur[i] * w0[i][3];
            v = v / (1.f + __expf(-v));
            o[i] = (short)f2bf(v);
        }
        *(b16x8*)&u16[(size_t)(m0 + j) * DI + d0] = o;
        #pragma unroll
        for (int i = 0; i < 8; i++) {
            win[0][i] = win[1][i];
            win[1][i] = win[2][i];
            win[2][i] = cur[i];
        }
    }
}

// load A-row decay factors and detect A[d,n] == -(n+1) structure (wave-uniform)
__device__ __forceinline__ bool load_A(const float* __restrict__ A_log, int d, float* Av) {
    bool fast = true;
    #pragma unroll
    for (int n = 0; n < NST; n++) {
        Av[n] = -__expf(A_log[(size_t)d * NST + n]);
        fast = fast && (fabsf(Av[n] + (float)(n + 1)) < 1e-4f * (float)(n + 1));
    }
    return fast;
}

// log-depth decay powers: en[n] = e1^(n+1), depth ~5, 16-way ILP
__device__ __forceinline__ void en_tree(float e1, float* en) {
    float e2 = e1 * e1, e3 = e2 * e1, e4 = e2 * e2, e8 = e4 * e4, e12 = e8 * e4;
    en[0] = e1;        en[1] = e2;        en[2] = e3;        en[3] = e4;
    en[4] = e4 * e1;   en[5] = e4 * e2;   en[6] = e4 * e3;   en[7] = e8;
    en[8] = e8 * e1;   en[9] = e8 * e2;   en[10] = e8 * e3;  en[11] = e12;
    en[12] = e12 * e1; en[13] = e12 * e2; en[14] = e12 * e3; en[15] = e8 * e8;
}

// ---------------- scan pass A: per-chunk local recurrence from h=0 ----------------
// Launched for chunks 0..NCH-2 only (last chunk's summary is never consumed).
__global__ __launch_bounds__(256) void scan_partial(const unsigned short* __restrict__ delta16,
                                                    const unsigned short* __restrict__ u16,
                                                    const float* __restrict__ xdbl,
                                                    const float* __restrict__ A_log,
                                                    float* __restrict__ sumd,
                                                    float* __restrict__ hend) {
    int d = blockIdx.x * 256 + threadIdx.x;
    int ch = blockIdx.y, b = blockIdx.z;
    size_t bL = (size_t)b * LSEQ + (size_t)ch * CHL;
    float Av[NST], h[NST];
    const bool fast = load_A(A_log, d, Av);
    #pragma unroll
    for (int n = 0; n < NST; n++) h[n] = 0.f;
    float S = 0.f;
    #pragma unroll 2
    for (int l = 0; l < CHL; l++) {
        size_t r = bL + l;
        float dl = bf2f(delta16[r * DI + d]);
        float uu = bf2f(u16[r * DI + d]);
        S += dl;
        float du = dl * uu;
        const float* xr = &xdbl[r * 64 + 32];
        float Bv[NST];
        #pragma unroll
        for (int t = 0; t < 4; t++) *(fx4*)&Bv[t * 4] = *(const fx4*)(xr + t * 4);
        float en[NST];
        if (fast) {
            en_tree(__expf(-dl), en);
        } else {
            #pragma unroll
            for (int n = 0; n < NST; n++) en[n] = __expf(dl * Av[n]);
        }
        #pragma unroll
        for (int n = 0; n < NST; n++) h[n] = h[n] * en[n] + du * Bv[n];
    }
    size_t base = ((size_t)(b * NCH + ch) * NST) * DI + d;
    #pragma unroll
    for (int n = 0; n < NST; n++) hend[base + (size_t)n * DI] = h[n];
    sumd[(size_t)(b * NCH + ch) * DI + d] = S;
}

// ---------------- scan pass B: carry chunk-boundary states (IN-PLACE over hend) ----
__global__ __launch_bounds__(256) void scan_carry(const float* __restrict__ sumd,
                                                  float* __restrict__ hend,
                                                  const float* __restrict__ A_log) {
    int d = blockIdx.x * 256 + threadIdx.x;
    int b = blockIdx.y;
    float Av[NST], h[NST];
    #pragma unroll
    for (int n = 0; n < NST; n++) {
        Av[n] = -__expf(A_log[(size_t)d * NST + n]);
        h[n] = 0.f;
    }
    for (int k = 0; k < NCH; k++) {
        size_t base = ((size_t)(b * NCH + k) * NST) * DI + d;
        if (k < NCH - 1) {
            float S = sumd[(size_t)(b * NCH + k) * DI + d];
            float he[NST];
            #pragma unroll
            for (int n = 0; n < NST; n++) he[n] = hend[base + (size_t)n * DI];
            #pragma unroll
            for (int n = 0; n < NST; n++) hend[base + (size_t)n * DI] = h[n];
            #pragma unroll
            for (int n = 0; n < NST; n++) h[n] = h[n] * __expf(S * Av[n]) + he[n];
        } else {
            #pragma unroll
            for (int n = 0; n < NST; n++) hend[base + (size_t)n * DI] = h[n];
        }
    }
}

// ---------------- scan pass C: final chunk recurrence + gating (y in-place over u) ----
__global__ __launch_bounds__(256) void scan_final(const unsigned short* __restrict__ delta16,
                                                  const unsigned short* u16,
                                                  const unsigned short* __restrict__ xz16,
                                                  const float* __restrict__ xdbl,
                                                  const float* __restrict__ A_log,
                                                  const float* __restrict__ Dp,
                                                  const float* __restrict__ hin,
                                                  unsigned short* y16) {
    int d = blockIdx.x * 256 + threadIdx.x;
    int ch = blockIdx.y, b = blockIdx.z;
    size_t bL = (size_t)b * LSEQ + (size_t)ch * CHL;
    float Av[NST], h[NST];
    const bool fast = load_A(A_log, d, Av);
    size_t base = ((size_t)(b * NCH + ch) * NST) * DI + d;
    #pragma unroll
    for (int n = 0; n < NST; n++) h[n] = hin[base + (size_t)n * DI];
    float Dd = Dp[d];
    #pragma unroll 2
    for (int l = 0; l < CHL; l++) {
        size_t r = bL + l;
        float dl = bf2f(delta16[r * DI + d]);
        float uu = bf2f(u16[r * DI + d]);
        float zz = bf2f(xz16[r * (2 * DI) + DI + d]);
        float du = dl * uu;
        const float* xr = &xdbl[r * 64 + 32];
        float Bv[NST], Cv[NST];
        #pragma unroll
        for (int t = 0; t < 4; t++) {
            *(fx4*)&Bv[t * 4] = *(const fx4*)(xr + t * 4);
            *(fx4*)&Cv[t * 4] = *(const fx4*)(xr + 16 + t * 4);
        }
        float en[NST];
        if (fast) {
            en_tree(__expf(-dl), en);
        } else {
            #pragma unroll
            for (int n = 0; n < NST; n++) en[n] = __expf(dl * Av[n]);
        }
        float y = 0.f;
        #pragma unroll
        for (int n = 0; n < NST; n++) {
            h[n] = h[n] * en[n] + du * Bv[n];
            y += h[n] * Cv[n];
        }
        y = (y + uu * Dd) * (zz / (1.f + __expf(-zz)));
        y16[r * DI + d] = f2bf(y);
    }
}

// ---------------- LayerNorm(a + res) * g + b — one wave per row, no LDS ----------------
// AIN/RIN: 0 = f32 input, 1 = bf16 input. OUT: 0 = f32, 1 = bf16.
template <int AIN, int RIN, int OUT>
__global__ __launch_bounds__(256) void ln_kernel(const void* __restrict__ a,
                                                 const void* __restrict__ res,
                                                 const float* __restrict__ g,
                                                 const float* __restrict__ bta,
                                                 void* __restrict__ out) {
    int lane = threadIdx.x & 63;
    int row = blockIdx.x * 4 + (threadIdx.x >> 6);
    size_t base = (size_t)row * DM;
    int c0 = lane * 8;
    float av[8], rv[8];
    if (AIN == 0) {
        *(fx4*)&av[0] = *(const fx4*)&((const float*)a)[base + c0];
        *(fx4*)&av[4] = *(const fx4*)&((const float*)a)[base + c0 + 4];
    } else {
        b16x8 t = *(const b16x8*)&((const unsigned short*)a)[base + c0];
        #pragma unroll
        for (int i = 0; i < 8; i++) av[i] = bf2f((unsigned short)t[i]);
    }
    if (RIN == 0) {
        *(fx4*)&rv[0] = *(const fx4*)&((const float*)res)[base + c0];
        *(fx4*)&rv[4] = *(const fx4*)&((const float*)res)[base + c0 + 4];
    } else {
        b16x8 t = *(const b16x8*)&((const unsigned short*)res)[base + c0];
        #pragma unroll
        for (int i = 0; i < 8; i++) rv[i] = bf2f((unsigned short)t[i]);
    }
    float v[8], s = 0.f, q = 0.f;
    #pragma unroll
    for (int i = 0; i < 8; i++) {
        v[i] = av[i] + rv[i];
        s += v[i];
        q += v[i] * v[i];
    }
    #pragma unroll
    for (int m = 32; m >= 1; m >>= 1) {
        s += __shfl_xor(s, m);
        q += __shfl_xor(q, m);
    }
    float mu = s * (1.f / DM);
    float var = q * (1.f / DM) - mu * mu;
    float rsg = rsqrtf(var + 1e-12f);
    float gv[8], bv[8];
    *(fx4*)&gv[0] = *(const fx4*)&g[c0];
    *(fx4*)&gv[4] = *(const fx4*)&g[c0 + 4];
    *(fx4*)&bv[0] = *(const fx4*)&bta[c0];
    *(fx4*)&bv[4] = *(const fx4*)&bta[c0 + 4];
    if (OUT == 0) {
        fx4 o0, o1;
        #pragma unroll
        for (int i = 0; i < 4; i++) o0[i] = (v[i] - mu) * rsg * gv[i] + bv[i];
        #pragma unroll
        for (int i = 0; i < 4; i++) o1[i] = (v[4 + i] - mu) * rsg * gv[4 + i] + bv[4 + i];
        *(fx4*)&((float*)out)[base + c0] = o0;
        *(fx4*)&((float*)out)[base + c0 + 4] = o1;
    } else {
        b16x8 o;
        #pragma unroll
        for (int i = 0; i < 8; i++) o[i] = (short)f2bf((v[i] - mu) * rsg * gv[i] + bv[i]);
        *(b16x8*)&((unsigned short*)out)[base + c0] = o;
    }
}

static size_t align256(size_t b) { return (b + 255) & ~(size_t)255; }

// exact footprint for a group of Gb batches (R = Gb*LSEQ rows)
static size_t tier_need(size_t Gb) {
    size_t R = Gb * LSEQ;
    size_t w = 0;
    w += align256((size_t)2 * DI * DM * 2);   // win16
    w += align256((size_t)64 * DI * 2);       // wxp16
    w += align256((size_t)DM * DI * 2);       // wop16
    w += align256((size_t)4 * DM * DM * 2);   // ww116
    w += align256((size_t)DM * 4 * DM * 2);   // ww216
    w += align256((size_t)DI * DTR * 2);      // wdt16
    w += align256(R * 2048 * 2);              // xz16 | f16
    w += align256(R * 1024 * 2);              // u16 | y16 (in-place)
    w += align256(R * 1024 * 2);              // delta16 -> mm16 -> w2o16
    w += align256(R * 64 * 4);                // xdbl
    w += align256(R * 32 * 2);                // dt16
    w += align256(R * 512 * 2);               // x16 | h16
    w += align256(Gb * NCH * DI * 4);         // sumd
    w += align256(Gb * NCH * NST * DI * 4);   // hend (in-place hin)
    return w;
}

extern "C" void kernel_launch(void* const* d_in, const int* in_sizes, int n_in,
                              void* d_out, int out_size, void* d_ws, size_t ws_size,
                              hipStream_t stream) {
    const float* x_in   = (const float*)d_in[0];
    const float* inpw   = (const float*)d_in[1];
    const float* convw  = (const float*)d_in[2];
    const float* convb  = (const float*)d_in[3];
    const float* xprojw = (const float*)d_in[4];
    const float* dtw    = (const float*)d_in[5];
    const float* dtb    = (const float*)d_in[6];
    const float* A_log  = (const float*)d_in[7];
    const float* Dp     = (const float*)d_in[8];
    const float* outpw  = (const float*)d_in[9];
    const float* ln1g   = (const float*)d_in[10];
    const float* ln1b   = (const float*)d_in[11];
    const float* w1w    = (const float*)d_in[12];
    const float* w1b    = (const float*)d_in[13];
    const float* w2w    = (const float*)d_in[14];
    const float* w2b    = (const float*)d_in[15];
    const float* ln2g   = (const float*)d_in[16];
    const float* ln2b   = (const float*)d_in[17];

    // pick largest batch-group that fits ws_size (deterministic: ws_size is fixed)
    int G = 1;
    const int tiers[5] = {32, 16, 8, 4, 2};
    for (int t = 0; t < 5; t++) {
        if (ws_size >= tier_need((size_t)tiers[t])) { G = tiers[t]; break; }
    }
    const size_t R = (size_t)G * LSEQ;   // rows per group

    char* w = (char*)d_ws;
    auto alloc = [&](size_t bytes) { char* p = w; w += align256(bytes); return p; };

    unsigned short* win16 = (unsigned short*)alloc((size_t)2 * DI * DM * 2);
    unsigned short* wxp16 = (unsigned short*)alloc((size_t)64 * DI * 2);
    unsigned short* wop16 = (unsigned short*)alloc((size_t)DM * DI * 2);
    unsigned short* ww116 = (unsigned short*)alloc((size_t)4 * DM * DM * 2);
    unsigned short* ww216 = (unsigned short*)alloc((size_t)DM * 4 * DM * 2);
    unsigned short* wdt16 = (unsigned short*)alloc((size_t)DI * DTR * 2);
    unsigned short* xz16  = (unsigned short*)alloc(R * 2048 * 2);  // -> f16 after scan
    unsigned short* u16   = (unsigned short*)alloc(R * 1024 * 2);  // -> y16 in-place
    unsigned short* dreg  = (unsigned short*)alloc(R * 1024 * 2);  // delta16 -> mm16 -> w2o16
    float*          xdbl  = (float*)alloc(R * 64 * 4);
    unsigned short* dt16  = (unsigned short*)alloc(R * 32 * 2);
    unsigned short* x16   = (unsigned short*)alloc(R * 512 * 2);   // -> h16
    float*          sumd  = (float*)alloc((size_t)G * NCH * DI * 4);
    float*          hend  = (float*)alloc((size_t)G * NCH * NST * DI * 4);

    unsigned short* delta16 = dreg;        // bf16 delta [R,1024]
    unsigned short* y16 = u16;             // in-place over u16
    unsigned short* f16 = xz16;            // after z consumed by scan
    unsigned short* mm16 = dreg;           // after delta consumed by scan  [R,512]
    unsigned short* w2o16 = dreg;          // after mm16 consumed by LN1    [R,512]
    unsigned short* h16  = x16;            // after x16 consumed by GEMM1

    dim3 blk(256);
    // weight casts (once)
    cast_kernel<<<(2 * DI * DM / 4 + 255) / 256, blk, 0, stream>>>(inpw, win16, 2 * DI * DM / 4);
    cast_kernel<<<(64 * DI / 4 + 255) / 256, blk, 0, stream>>>(xprojw, wxp16, 64 * DI / 4);
    cast_kernel<<<(DM * DI / 4 + 255) / 256, blk, 0, stream>>>(outpw, wop16, DM * DI / 4);
    cast_kernel<<<(4 * DM * DM / 4 + 255) / 256, blk, 0, stream>>>(w1w, ww116, 4 * DM * DM / 4);
    cast_kernel<<<(DM * 4 * DM / 4 + 255) / 256, blk, 0, stream>>>(w2w, ww216, DM * 4 * DM / 4);
    cast_kernel<<<(DI * DTR / 4 + 255) / 256, blk, 0, stream>>>(dtw, wdt16, DI * DTR / 4);

    for (int grp = 0; grp < NBATCH / G; grp++) {
        const size_t rb = (size_t)grp * R;                 // global row base
        const float* xg = x_in + rb * DM;
        // 0. cast input rows
        cast_kernel<<<(int)(R * DM / 4 / 256), blk, 0, stream>>>(xg, x16, (int)(R * DM / 4));
        // 1. xz = x @ in_proj_w^T   [R, 2048] bf16
        gemm_bf16<128, 64, 1, false><<<dim3(2 * DI / 128, R / 128), blk, 0, stream>>>(
            x16, win16, nullptr, xz16, 2 * DI, DM, nullptr);
        // 2. conv + silu -> u16 (strip-of-8 rolling window)
        conv_silu_kernel<<<(int)(R / 16), blk, 0, stream>>>(xz16, convw, convb, u16);
        // 3. x_dbl = u @ x_proj_w^T  [R, 64] f32  (+ fused dt16 extract, cols<32)
        gemm_bf16<64, 64, 5, false><<<dim3(1, R / 128), blk, 0, stream>>>(
            u16, wxp16, nullptr, xdbl, 64, DI, dt16);
        // 4. delta = softplus(dt @ dt_proj_w^T + b) -> bf16
        gemm_bf16<128, 32, 4, true><<<dim3(DI / 128, R / 128), blk, 0, stream>>>(
            dt16, wdt16, dtb, delta16, DI, DTR, nullptr);
        // 5. chunked parallel scan (3 passes; pass A skips last chunk; carry in-place)
        scan_partial<<<dim3(DI / 256, NCH - 1, G), blk, 0, stream>>>(
            delta16, u16, xdbl, A_log, sumd, hend);
        scan_carry<<<dim3(DI / 256, G), blk, 0, stream>>>(sumd, hend, A_log);
        scan_final<<<dim3(DI / 256, NCH, G), blk, 0, stream>>>(
            delta16, u16, xz16, xdbl, A_log, Dp, hend, y16);
        // 6. mamba_out = y @ out_proj_w^T  [R, 512] bf16 (over dreg)
        gemm_bf16<128, 64, 1, false><<<dim3(DM / 128, R / 128), blk, 0, stream>>>(
            y16, wop16, nullptr, mm16, DM, DI, nullptr);
        // 7. h16 = LN(mamba_out + x)   (bf16 out; feeds GEMM8 and LN2 residual)
        ln_kernel<1, 0, 1><<<(int)(R / 4), blk, 0, stream>>>(mm16, xg, ln1g, ln1b, h16);
        // 8. f = gelu(h @ w1^T + b1)  [R, 2048] bf16 (aliases xz16)
        gemm_bf16<128, 64, 2, true><<<dim3(4 * DM / 128, R / 128), blk, 0, stream>>>(
            h16, ww116, w1b, f16, 4 * DM, DM, nullptr);
        // 9. w2o = f @ w2^T + b2  [R, 512] bf16 (aliases mm16)
        gemm_bf16<128, 64, 1, true><<<dim3(DM / 128, R / 128), blk, 0, stream>>>(
            f16, ww216, w2b, w2o16, DM, 4 * DM, nullptr);
        // 10. out = LN(w2o + h)  f32
        ln_kernel<1, 1, 0><<<(int)(R / 4), blk, 0, stream>>>(w2o16, h16, ln2g, ln2b,
                                                             (float*)d_out + rb * DM);
    }
}

// Round 15
// 1585.708 us; speedup vs baseline: 1.0274x; 1.0274x over previous
//
#include <hip/hip_runtime.h>
#include <hip/hip_bf16.h>

#define DM 512
#define DI 1024
#define DC 4
#define DTR 32
#define NST 16
#define LSEQ 2048
#define NBATCH 32
#define NCH 32
#define CHL 64    // LSEQ / NCH

typedef __attribute__((ext_vector_type(8))) short b16x8;
typedef __attribute__((ext_vector_type(4))) float fx4;
typedef __attribute__((ext_vector_type(4))) unsigned short u16x4;

__device__ __forceinline__ unsigned short f2bf(float f) {
    union { float f; unsigned u; } x; x.f = f;
    unsigned r = x.u + 0x7fffu + ((x.u >> 16) & 1u);
    return (unsigned short)(r >> 16);
}
__device__ __forceinline__ float bf2f(unsigned short u) {
    union { unsigned u; float f; } x; x.u = ((unsigned)u) << 16;
    return x.f;
}

// ---------------- cast fp32 -> bf16 (vec4) ----------------
__global__ __launch_bounds__(256) void cast_kernel(const float* __restrict__ src,
                                                   unsigned short* __restrict__ dst, int n4) {
    int i = blockIdx.x * 256 + threadIdx.x;
    if (i < n4) {
        fx4 v = *(const fx4*)&src[(size_t)i * 4];
        u16x4 o;
        #pragma unroll
        for (int j = 0; j < 4; j++) o[j] = f2bf(v[j]);
        *(u16x4*)&dst[(size_t)i * 4] = o;
    }
}

// ---------------- MFMA bf16 GEMM: C[m,n] = sum_k A[m,k]*W[n,k] ----------------
// R13 configuration — measured best (146us/GEMM, total 1597us). Single-buffer
// 2-barrier loop, 32KB LDS, XOR swizzle S(o)=o^(((o>>7)&3)<<5) applied
// both-sides (pre-swizzled global source + swizzled read; rule #21).
// Five structure experiments (R4/R5/R6 dyn-db prefetch = races; R9 k-major =
// lost coalescing; R14 static ping-pong = correct but 64KB LDS halved
// residency, 20% occ vs 29%) all lost to this form — inter-block TLP is the
// overlap mechanism here (m99/m100/m114). Do not restructure.
// EPI: 0=f32, 1=bf16, 2=gelu->bf16, 3=softplus->f32, 4=softplus->bf16,
//      5=f32 + bf16 copy of cols<32 into aux (xdbl + dt16 fusion)
template <int BN, int BK, int EPI, bool HAS_BIAS>
__global__ __launch_bounds__(256, 3) void gemm_bf16(const unsigned short* __restrict__ A,
                                                    const unsigned short* __restrict__ W,
                                                    const float* __restrict__ bias,
                                                    void* __restrict__ Cout, int N, int K,
                                                    unsigned short* __restrict__ aux) {
    constexpr int BM = 128;
    constexpr int RSH = (BK == 64) ? 7 : 6;   // log2(row bytes)
    __shared__ __align__(16) unsigned short As[BM * BK];
    __shared__ __align__(16) unsigned short Ws[BN * BK];
    const int tid = threadIdx.x;
    const int wave = tid >> 6, lane = tid & 63;
    const int lr = lane & 15, lg = lane >> 4;
    // XCD swizzle: same-XCD blocks get consecutive tiles (share A panels in L2)
    const int ntx = gridDim.x;
    const int tot = ntx * gridDim.y;
    const int lin = blockIdx.y * ntx + blockIdx.x;
    const int cpx = tot >> 3;
    const int swz = (lin & 7) * cpx + (lin >> 3);
    const int m0 = (swz / ntx) * BM, n0 = (swz % ntx) * BN;
    const int wm0 = (wave >> 1) * 64, wn0 = (wave & 1) * (BN / 2);
    constexpr int NR = BN / 32;
    fx4 acc[4][NR];
    #pragma unroll
    for (int i = 0; i < 4; i++)
        #pragma unroll
        for (int j = 0; j < NR; j++) acc[i][j] = fx4{0.f, 0.f, 0.f, 0.f};

    for (int k0 = 0; k0 < K; k0 += BK) {
        #pragma unroll
        for (int i = 0; i < (BM * BK / 8) / 256; i++) {
            int ob = (i * 4 + wave) * 1024;      // wave-uniform byte base
            int o = ob + lane * 16;              // this lane's dest byte
            int s = (BK == 64) ? (o ^ (((o >> 7) & 3) << 5)) : o;  // source perm
            int row = s >> RSH, cbyte = s & (2 * BK - 1);
            const unsigned short* g = A + (size_t)(m0 + row) * K + k0 + (cbyte >> 1);
            __builtin_amdgcn_global_load_lds(
                (const __attribute__((address_space(1))) unsigned int*)g,
                (__attribute__((address_space(3))) unsigned int*)&As[ob >> 1], 16, 0, 0);
        }
        #pragma unroll
        for (int i = 0; i < (BN * BK / 8) / 256; i++) {
            int ob = (i * 4 + wave) * 1024;
            int o = ob + lane * 16;
            int s = (BK == 64) ? (o ^ (((o >> 7) & 3) << 5)) : o;
            int row = s >> RSH, cbyte = s & (2 * BK - 1);
            const unsigned short* g = W + (size_t)(n0 + row) * K + k0 + (cbyte >> 1);
            __builtin_amdgcn_global_load_lds(
                (const __attribute__((address_space(1))) unsigned int*)g,
                (__attribute__((address_space(3))) unsigned int*)&Ws[ob >> 1], 16, 0, 0);
        }
        __syncthreads();
        #pragma unroll
        for (int ks = 0; ks < BK / 32; ks++) {
            b16x8 af[4], bfr[NR];
            #pragma unroll
            for (int mi = 0; mi < 4; mi++) {
                int ar = wm0 + mi * 16 + lr;
                int ab = (ar * BK + ks * 32 + lg * 8) * 2;
                if (BK == 64) ab ^= (ar & 3) << 5;
                af[mi] = *(const b16x8*)&As[ab >> 1];
            }
            #pragma unroll
            for (int ni = 0; ni < NR; ni++) {
                int wr = wn0 + ni * 16 + lr;
                int wb = (wr * BK + ks * 32 + lg * 8) * 2;
                if (BK == 64) wb ^= (wr & 3) << 5;
                bfr[ni] = *(const b16x8*)&Ws[wb >> 1];
            }
            #pragma unroll
            for (int mi = 0; mi < 4; mi++)
                #pragma unroll
                for (int ni = 0; ni < NR; ni++)
                    acc[mi][ni] = __builtin_amdgcn_mfma_f32_16x16x32_bf16(af[mi], bfr[ni],
                                                                         acc[mi][ni], 0, 0, 0);
        }
        __syncthreads();
    }
    #pragma unroll
    for (int mi = 0; mi < 4; mi++) {
        #pragma unroll
        for (int ni = 0; ni < NR; ni++) {
            #pragma unroll
            for (int j2 = 0; j2 < 4; j2++) {
                int row = m0 + wm0 + mi * 16 + lg * 4 + j2;
                int col = n0 + wn0 + ni * 16 + lr;
                float v = acc[mi][ni][j2];
                if (HAS_BIAS) v += bias[col];
                size_t o = (size_t)row * N + col;
                if (EPI == 0) {
                    ((float*)Cout)[o] = v;
                } else if (EPI == 1) {
                    ((unsigned short*)Cout)[o] = f2bf(v);
                } else if (EPI == 2) {
                    v = 0.5f * v * (1.f + erff(v * 0.70710678118654752f));
                    ((unsigned short*)Cout)[o] = f2bf(v);
                } else if (EPI == 3) {
                    v = (v > 20.f) ? v : log1pf(__expf(v));
                    ((float*)Cout)[o] = v;
                } else if (EPI == 4) {
                    v = (v > 20.f) ? v : log1pf(__expf(v));
                    ((unsigned short*)Cout)[o] = f2bf(v);
                } else {
                    ((float*)Cout)[o] = v;
                    if (col < DTR) aux[(size_t)row * DTR + col] = f2bf(v);
                }
            }
        }
    }
}

// ---------------- depthwise causal conv (4 taps) + SiLU, strip-of-8 rolling window ----
__global__ __launch_bounds__(256) void conv_silu_kernel(const unsigned short* __restrict__ xz16,
                                                        const float* __restrict__ cw,
                                                        const float* __restrict__ cb,
                                                        unsigned short* __restrict__ u16) {
    int idx = blockIdx.x * 256 + threadIdx.x;  // (R/8) * 128
    int strip = idx >> 7;
    int d0 = (idx & 127) << 3;
    int m0 = strip * 8;
    int l0 = m0 & (LSEQ - 1);
    fx4 w0[8];
    float bias[8];
    #pragma unroll
    for (int j = 0; j < 8; j++) {
        bias[j] = cb[d0 + j];
        w0[j] = *(const fx4*)&cw[(d0 + j) * 4];
    }
    float win[3][8];
    #pragma unroll
    for (int t = 0; t < 3; t++) {
        int lm = l0 - 3 + t;
        if (lm >= 0) {
            b16x8 xv = *(const b16x8*)&xz16[(size_t)(m0 - 3 + t) * (2 * DI) + d0];
            #pragma unroll
            for (int i = 0; i < 8; i++) win[t][i] = bf2f((unsigned short)xv[i]);
        } else {
            #pragma unroll
            for (int i = 0; i < 8; i++) win[t][i] = 0.f;
        }
    }
    #pragma unroll
    for (int j = 0; j < 8; j++) {
        float cur[8];
        b16x8 xv = *(const b16x8*)&xz16[(size_t)(m0 + j) * (2 * DI) + d0];
        #pragma unroll
        for (int i = 0; i < 8; i++) cur[i] = bf2f((unsigned short)xv[i]);
        b16x8 o;
        #pragma unroll
        for (int i = 0; i < 8; i++) {
            float v = bias[i] + win[0][i] * w0[i][0] + win[1][i] * w0[i][1] +
                      win[2][i] * w0[i][2] + cur[i] * w0[i][3];
            v = v / (1.f + __expf(-v));
            o[i] = (short)f2bf(v);
        }
        *(b16x8*)&u16[(size_t)(m0 + j) * DI + d0] = o;
        #pragma unroll
        for (int i = 0; i < 8; i++) {
            win[0][i] = win[1][i];
            win[1][i] = win[2][i];
            win[2][i] = cur[i];
        }
    }
}

// load A-row decay factors and detect A[d,n] == -(n+1) structure (wave-uniform)
__device__ __forceinline__ bool load_A(const float* __restrict__ A_log, int d, float* Av) {
    bool fast = true;
    #pragma unroll
    for (int n = 0; n < NST; n++) {
        Av[n] = -__expf(A_log[(size_t)d * NST + n]);
        fast = fast && (fabsf(Av[n] + (float)(n + 1)) < 1e-4f * (float)(n + 1));
    }
    return fast;
}

// log-depth decay powers: en[n] = e1^(n+1), depth ~5, 16-way ILP
__device__ __forceinline__ void en_tree(float e1, float* en) {
    float e2 = e1 * e1, e3 = e2 * e1, e4 = e2 * e2, e8 = e4 * e4, e12 = e8 * e4;
    en[0] = e1;        en[1] = e2;        en[2] = e3;        en[3] = e4;
    en[4] = e4 * e1;   en[5] = e4 * e2;   en[6] = e4 * e3;   en[7] = e8;
    en[8] = e8 * e1;   en[9] = e8 * e2;   en[10] = e8 * e3;  en[11] = e12;
    en[12] = e12 * e1; en[13] = e12 * e2; en[14] = e12 * e3; en[15] = e8 * e8;
}

// ---------------- scan pass A: per-chunk local recurrence from h=0 ----------------
// Launched for chunks 0..NCH-2 only (last chunk's summary is never consumed).
__global__ __launch_bounds__(256) void scan_partial(const unsigned short* __restrict__ delta16,
                                                    const unsigned short* __restrict__ u16,
                                                    const float* __restrict__ xdbl,
                                                    const float* __restrict__ A_log,
                                                    float* __restrict__ sumd,
                                                    float* __restrict__ hend) {
    int d = blockIdx.x * 256 + threadIdx.x;
    int ch = blockIdx.y, b = blockIdx.z;
    size_t bL = (size_t)b * LSEQ + (size_t)ch * CHL;
    float Av[NST], h[NST];
    const bool fast = load_A(A_log, d, Av);
    #pragma unroll
    for (int n = 0; n < NST; n++) h[n] = 0.f;
    float S = 0.f;
    #pragma unroll 2
    for (int l = 0; l < CHL; l++) {
        size_t r = bL + l;
        float dl = bf2f(delta16[r * DI + d]);
        float uu = bf2f(u16[r * DI + d]);
        S += dl;
        float du = dl * uu;
        const float* xr = &xdbl[r * 64 + 32];
        float Bv[NST];
        #pragma unroll
        for (int t = 0; t < 4; t++) *(fx4*)&Bv[t * 4] = *(const fx4*)(xr + t * 4);
        float en[NST];
        if (fast) {
            en_tree(__expf(-dl), en);
        } else {
            #pragma unroll
            for (int n = 0; n < NST; n++) en[n] = __expf(dl * Av[n]);
        }
        #pragma unroll
        for (int n = 0; n < NST; n++) h[n] = h[n] * en[n] + du * Bv[n];
    }
    size_t base = ((size_t)(b * NCH + ch) * NST) * DI + d;
    #pragma unroll
    for (int n = 0; n < NST; n++) hend[base + (size_t)n * DI] = h[n];
    sumd[(size_t)(b * NCH + ch) * DI + d] = S;
}

// ---------------- scan pass B: carry chunk-boundary states (IN-PLACE over hend) ----
__global__ __launch_bounds__(256) void scan_carry(const float* __restrict__ sumd,
                                                  float* __restrict__ hend,
                                                  const float* __restrict__ A_log) {
    int d = blockIdx.x * 256 + threadIdx.x;
    int b = blockIdx.y;
    float Av[NST], h[NST];
    #pragma unroll
    for (int n = 0; n < NST; n++) {
        Av[n] = -__expf(A_log[(size_t)d * NST + n]);
        h[n] = 0.f;
    }
    for (int k = 0; k < NCH; k++) {
        size_t base = ((size_t)(b * NCH + k) * NST) * DI + d;
        if (k < NCH - 1) {
            float S = sumd[(size_t)(b * NCH + k) * DI + d];
            float he[NST];
            #pragma unroll
            for (int n = 0; n < NST; n++) he[n] = hend[base + (size_t)n * DI];
            #pragma unroll
            for (int n = 0; n < NST; n++) hend[base + (size_t)n * DI] = h[n];
            #pragma unroll
            for (int n = 0; n < NST; n++) h[n] = h[n] * __expf(S * Av[n]) + he[n];
        } else {
            #pragma unroll
            for (int n = 0; n < NST; n++) hend[base + (size_t)n * DI] = h[n];
        }
    }
}

// ---------------- scan pass C: final chunk recurrence + gating (y in-place over u) ----
__global__ __launch_bounds__(256) void scan_final(const unsigned short* __restrict__ delta16,
                                                  const unsigned short* u16,
                                                  const unsigned short* __restrict__ xz16,
                                                  const float* __restrict__ xdbl,
                                                  const float* __restrict__ A_log,
                                                  const float* __restrict__ Dp,
                                                  const float* __restrict__ hin,
                                                  unsigned short* y16) {
    int d = blockIdx.x * 256 + threadIdx.x;
    int ch = blockIdx.y, b = blockIdx.z;
    size_t bL = (size_t)b * LSEQ + (size_t)ch * CHL;
    float Av[NST], h[NST];
    const bool fast = load_A(A_log, d, Av);
    size_t base = ((size_t)(b * NCH + ch) * NST) * DI + d;
    #pragma unroll
    for (int n = 0; n < NST; n++) h[n] = hin[base + (size_t)n * DI];
    float Dd = Dp[d];
    #pragma unroll 2
    for (int l = 0; l < CHL; l++) {
        size_t r = bL + l;
        float dl = bf2f(delta16[r * DI + d]);
        float uu = bf2f(u16[r * DI + d]);
        float zz = bf2f(xz16[r * (2 * DI) + DI + d]);
        float du = dl * uu;
        const float* xr = &xdbl[r * 64 + 32];
        float Bv[NST], Cv[NST];
        #pragma unroll
        for (int t = 0; t < 4; t++) {
            *(fx4*)&Bv[t * 4] = *(const fx4*)(xr + t * 4);
            *(fx4*)&Cv[t * 4] = *(const fx4*)(xr + 16 + t * 4);
        }
        float en[NST];
        if (fast) {
            en_tree(__expf(-dl), en);
        } else {
            #pragma unroll
            for (int n = 0; n < NST; n++) en[n] = __expf(dl * Av[n]);
        }
        float y = 0.f;
        #pragma unroll
        for (int n = 0; n < NST; n++) {
            h[n] = h[n] * en[n] + du * Bv[n];
            y += h[n] * Cv[n];
        }
        y = (y + uu * Dd) * (zz / (1.f + __expf(-zz)));
        y16[r * DI + d] = f2bf(y);
    }
}

// ---------------- LayerNorm(a + res) * g + b — one wave per row, no LDS ----------------
// AIN/RIN: 0 = f32 input, 1 = bf16 input. OUT: 0 = f32, 1 = bf16.
template <int AIN, int RIN, int OUT>
__global__ __launch_bounds__(256) void ln_kernel(const void* __restrict__ a,
                                                 const void* __restrict__ res,
                                                 const float* __restrict__ g,
                                                 const float* __restrict__ bta,
                                                 void* __restrict__ out) {
    int lane = threadIdx.x & 63;
    int row = blockIdx.x * 4 + (threadIdx.x >> 6);
    size_t base = (size_t)row * DM;
    int c0 = lane * 8;
    float av[8], rv[8];
    if (AIN == 0) {
        *(fx4*)&av[0] = *(const fx4*)&((const float*)a)[base + c0];
        *(fx4*)&av[4] = *(const fx4*)&((const float*)a)[base + c0 + 4];
    } else {
        b16x8 t = *(const b16x8*)&((const unsigned short*)a)[base + c0];
        #pragma unroll
        for (int i = 0; i < 8; i++) av[i] = bf2f((unsigned short)t[i]);
    }
    if (RIN == 0) {
        *(fx4*)&rv[0] = *(const fx4*)&((const float*)res)[base + c0];
        *(fx4*)&rv[4] = *(const fx4*)&((const float*)res)[base + c0 + 4];
    } else {
        b16x8 t = *(const b16x8*)&((const unsigned short*)res)[base + c0];
        #pragma unroll
        for (int i = 0; i < 8; i++) rv[i] = bf2f((unsigned short)t[i]);
    }
    float v[8], s = 0.f, q = 0.f;
    #pragma unroll
    for (int i = 0; i < 8; i++) {
        v[i] = av[i] + rv[i];
        s += v[i];
        q += v[i] * v[i];
    }
    #pragma unroll
    for (int m = 32; m >= 1; m >>= 1) {
        s += __shfl_xor(s, m);
        q += __shfl_xor(q, m);
    }
    float mu = s * (1.f / DM);
    float var = q * (1.f / DM) - mu * mu;
    float rsg = rsqrtf(var + 1e-12f);
    float gv[8], bv[8];
    *(fx4*)&gv[0] = *(const fx4*)&g[c0];
    *(fx4*)&gv[4] = *(const fx4*)&g[c0 + 4];
    *(fx4*)&bv[0] = *(const fx4*)&bta[c0];
    *(fx4*)&bv[4] = *(const fx4*)&bta[c0 + 4];
    if (OUT == 0) {
        fx4 o0, o1;
        #pragma unroll
        for (int i = 0; i < 4; i++) o0[i] = (v[i] - mu) * rsg * gv[i] + bv[i];
        #pragma unroll
        for (int i = 0; i < 4; i++) o1[i] = (v[4 + i] - mu) * rsg * gv[4 + i] + bv[4 + i];
        *(fx4*)&((float*)out)[base + c0] = o0;
        *(fx4*)&((float*)out)[base + c0 + 4] = o1;
    } else {
        b16x8 o;
        #pragma unroll
        for (int i = 0; i < 8; i++) o[i] = (short)f2bf((v[i] - mu) * rsg * gv[i] + bv[i]);
        *(b16x8*)&((unsigned short*)out)[base + c0] = o;
    }
}

static size_t align256(size_t b) { return (b + 255) & ~(size_t)255; }

// exact footprint for a group of Gb batches (R = Gb*LSEQ rows)
static size_t tier_need(size_t Gb) {
    size_t R = Gb * LSEQ;
    size_t w = 0;
    w += align256((size_t)2 * DI * DM * 2);   // win16
    w += align256((size_t)64 * DI * 2);       // wxp16
    w += align256((size_t)DM * DI * 2);       // wop16
    w += align256((size_t)4 * DM * DM * 2);   // ww116
    w += align256((size_t)DM * 4 * DM * 2);   // ww216
    w += align256((size_t)DI * DTR * 2);      // wdt16
    w += align256(R * 2048 * 2);              // xz16 | f16
    w += align256(R * 1024 * 2);              // u16 | y16 (in-place)
    w += align256(R * 1024 * 2);              // delta16 -> mm16 -> w2o16
    w += align256(R * 64 * 4);                // xdbl
    w += align256(R * 32 * 2);                // dt16
    w += align256(R * 512 * 2);               // x16 | h16
    w += align256(Gb * NCH * DI * 4);         // sumd
    w += align256(Gb * NCH * NST * DI * 4);   // hend (in-place hin)
    return w;
}

extern "C" void kernel_launch(void* const* d_in, const int* in_sizes, int n_in,
                              void* d_out, int out_size, void* d_ws, size_t ws_size,
                              hipStream_t stream) {
    const float* x_in   = (const float*)d_in[0];
    const float* inpw   = (const float*)d_in[1];
    const float* convw  = (const float*)d_in[2];
    const float* convb  = (const float*)d_in[3];
    const float* xprojw = (const float*)d_in[4];
    const float* dtw    = (const float*)d_in[5];
    const float* dtb    = (const float*)d_in[6];
    const float* A_log  = (const float*)d_in[7];
    const float* Dp     = (const float*)d_in[8];
    const float* outpw  = (const float*)d_in[9];
    const float* ln1g   = (const float*)d_in[10];
    const float* ln1b   = (const float*)d_in[11];
    const float* w1w    = (const float*)d_in[12];
    const float* w1b    = (const float*)d_in[13];
    const float* w2w    = (const float*)d_in[14];
    const float* w2b    = (const float*)d_in[15];
    const float* ln2g   = (const float*)d_in[16];
    const float* ln2b   = (const float*)d_in[17];

    // pick largest batch-group that fits ws_size (deterministic: ws_size is fixed)
    int G = 1;
    const int tiers[5] = {32, 16, 8, 4, 2};
    for (int t = 0; t < 5; t++) {
        if (ws_size >= tier_need((size_t)tiers[t])) { G = tiers[t]; break; }
    }
    const size_t R = (size_t)G * LSEQ;   // rows per group

    char* w = (char*)d_ws;
    auto alloc = [&](size_t bytes) { char* p = w; w += align256(bytes); return p; };

    unsigned short* win16 = (unsigned short*)alloc((size_t)2 * DI * DM * 2);
    unsigned short* wxp16 = (unsigned short*)alloc((size_t)64 * DI * 2);
    unsigned short* wop16 = (unsigned short*)alloc((size_t)DM * DI * 2);
    unsigned short* ww116 = (unsigned short*)alloc((size_t)4 * DM * DM * 2);
    unsigned short* ww216 = (unsigned short*)alloc((size_t)DM * 4 * DM * 2);
    unsigned short* wdt16 = (unsigned short*)alloc((size_t)DI * DTR * 2);
    unsigned short* xz16  = (unsigned short*)alloc(R * 2048 * 2);  // -> f16 after scan
    unsigned short* u16   = (unsigned short*)alloc(R * 1024 * 2);  // -> y16 in-place
    unsigned short* dreg  = (unsigned short*)alloc(R * 1024 * 2);  // delta16 -> mm16 -> w2o16
    float*          xdbl  = (float*)alloc(R * 64 * 4);
    unsigned short* dt16  = (unsigned short*)alloc(R * 32 * 2);
    unsigned short* x16   = (unsigned short*)alloc(R * 512 * 2);   // -> h16
    float*          sumd  = (float*)alloc((size_t)G * NCH * DI * 4);
    float*          hend  = (float*)alloc((size_t)G * NCH * NST * DI * 4);

    unsigned short* delta16 = dreg;        // bf16 delta [R,1024]
    unsigned short* y16 = u16;             // in-place over u16
    unsigned short* f16 = xz16;            // after z consumed by scan
    unsigned short* mm16 = dreg;           // after delta consumed by scan  [R,512]
    unsigned short* w2o16 = dreg;          // after mm16 consumed by LN1    [R,512]
    unsigned short* h16  = x16;            // after x16 consumed by GEMM1

    dim3 blk(256);
    // weight casts (once)
    cast_kernel<<<(2 * DI * DM / 4 + 255) / 256, blk, 0, stream>>>(inpw, win16, 2 * DI * DM / 4);
    cast_kernel<<<(64 * DI / 4 + 255) / 256, blk, 0, stream>>>(xprojw, wxp16, 64 * DI / 4);
    cast_kernel<<<(DM * DI / 4 + 255) / 256, blk, 0, stream>>>(outpw, wop16, DM * DI / 4);
    cast_kernel<<<(4 * DM * DM / 4 + 255) / 256, blk, 0, stream>>>(w1w, ww116, 4 * DM * DM / 4);
    cast_kernel<<<(DM * 4 * DM / 4 + 255) / 256, blk, 0, stream>>>(w2w, ww216, DM * 4 * DM / 4);
    cast_kernel<<<(DI * DTR / 4 + 255) / 256, blk, 0, stream>>>(dtw, wdt16, DI * DTR / 4);

    for (int grp = 0; grp < NBATCH / G; grp++) {
        const size_t rb = (size_t)grp * R;                 // global row base
        const float* xg = x_in + rb * DM;
        // 0. cast input rows
        cast_kernel<<<(int)(R * DM / 4 / 256), blk, 0, stream>>>(xg, x16, (int)(R * DM / 4));
        // 1. xz = x @ in_proj_w^T   [R, 2048] bf16
        gemm_bf16<128, 64, 1, false><<<dim3(2 * DI / 128, R / 128), blk, 0, stream>>>(
            x16, win16, nullptr, xz16, 2 * DI, DM, nullptr);
        // 2. conv + silu -> u16 (strip-of-8 rolling window)
        conv_silu_kernel<<<(int)(R / 16), blk, 0, stream>>>(xz16, convw, convb, u16);
        // 3. x_dbl = u @ x_proj_w^T  [R, 64] f32  (+ fused dt16 extract, cols<32)
        gemm_bf16<64, 64, 5, false><<<dim3(1, R / 128), blk, 0, stream>>>(
            u16, wxp16, nullptr, xdbl, 64, DI, dt16);
        // 4. delta = softplus(dt @ dt_proj_w^T + b) -> bf16
        gemm_bf16<128, 32, 4, true><<<dim3(DI / 128, R / 128), blk, 0, stream>>>(
            dt16, wdt16, dtb, delta16, DI, DTR, nullptr);
        // 5. chunked parallel scan (3 passes; pass A skips last chunk; carry in-place)
        scan_partial<<<dim3(DI / 256, NCH - 1, G), blk, 0, stream>>>(
            delta16, u16, xdbl, A_log, sumd, hend);
        scan_carry<<<dim3(DI / 256, G), blk, 0, stream>>>(sumd, hend, A_log);
        scan_final<<<dim3(DI / 256, NCH, G), blk, 0, stream>>>(
            delta16, u16, xz16, xdbl, A_log, Dp, hend, y16);
        // 6. mamba_out = y @ out_proj_w^T  [R, 512] bf16 (over dreg)
        gemm_bf16<128, 64, 1, false><<<dim3(DM / 128, R / 128), blk, 0, stream>>>(
            y16, wop16, nullptr, mm16, DM, DI, nullptr);
        // 7. h16 = LN(mamba_out + x)   (bf16 out; feeds GEMM8 and LN2 residual)
        ln_kernel<1, 0, 1><<<(int)(R / 4), blk, 0, stream>>>(mm16, xg, ln1g, ln1b, h16);
        // 8. f = gelu(h @ w1^T + b1)  [R, 2048] bf16 (aliases xz16)
        gemm_bf16<128, 64, 2, true><<<dim3(4 * DM / 128, R / 128), blk, 0, stream>>>(
            h16, ww116, w1b, f16, 4 * DM, DM, nullptr);
        // 9. w2o = f @ w2^T + b2  [R, 512] bf16 (aliases mm16)
        gemm_bf16<128, 64, 1, true><<<dim3(DM / 128, R / 128), blk, 0, stream>>>(
            f16, ww216, w2b, w2o16, DM, 4 * DM, nullptr);
        // 10. out = LN(w2o + h)  f32
        ln_kernel<1, 1, 0><<<(int)(R / 4), blk, 0, stream>>>(w2o16, h16, ln2g, ln2b,
                                                             (float*)d_out + rb * DM);
    }
}